// Round 6
// baseline (624.623 us; speedup 1.0000x reference)
//
#include <hip/hip_runtime.h>
#include <hip/hip_bf16.h>

// Problem constants
#define NN     8192      // nodes
#define D0     512       // x feature dim
#define D1     256       // hidden dim (W1 out)
#define D2     64        // z dim (W2 out)
#define NE     262144    // edges

typedef __attribute__((ext_vector_type(8)))  __bf16 bf16x8;
typedef __attribute__((ext_vector_type(16))) float  f32x16;
typedef __attribute__((ext_vector_type(4)))  float  f32x4;   // native vector for NT stores

// ---------------------------------------------------------------------------
// prep_k: fused zero(cnt,cur) + convw1t (W1 -> W1T bf16 hi/lo)
// grid = 16 + 128 blocks
// ---------------------------------------------------------------------------
__global__ __launch_bounds__(256) void prep_k(const float* __restrict__ W,
                                              int4* __restrict__ zero_region,
                                              __bf16* __restrict__ Th,
                                              __bf16* __restrict__ Tl) {
    const int bid = blockIdx.x;
    const int tid = threadIdx.x;
    if (bid < 16) {
        zero_region[bid * 256 + tid] = make_int4(0, 0, 0, 0);
    } else {
        __shared__ float t[32][33];
        const int cid = bid - 16;
        const int c0 = (cid & 7) * 32;      // D1/32 = 8
        const int k0 = (cid >> 3) * 32;     // D0/32 = 16
        {
            int tr  = tid >> 3;
            int tc4 = tid & 7;
            float4 v = *reinterpret_cast<const float4*>(&W[(k0 + tr) * D1 + c0 + tc4 * 4]);
            t[tr][tc4 * 4 + 0] = v.x;
            t[tr][tc4 * 4 + 1] = v.y;
            t[tr][tc4 * 4 + 2] = v.z;
            t[tr][tc4 * 4 + 3] = v.w;
        }
        __syncthreads();
        int c  = tid >> 3;
        int kq = (tid & 7) * 4;
        __bf16 hv[4], lv[4];
        #pragma unroll
        for (int j = 0; j < 4; ++j) {
            float f = t[kq + j][c];
            hv[j] = (__bf16)f;
            lv[j] = (__bf16)(f - (float)hv[j]);
        }
        *reinterpret_cast<uint2*>(&Th[(size_t)(c0 + c) * D0 + k0 + kq]) = *reinterpret_cast<uint2*>(hv);
        *reinterpret_cast<uint2*>(&Tl[(size_t)(c0 + c) * D0 + k0 + kq]) = *reinterpret_cast<uint2*>(lv);
    }
}

// ---------------------------------------------------------------------------
// GEMM1 via bf16 MFMA hi/lo split: xw1 = x @ W1
// 128x128 block, 4 waves (2x2), wave = 64x64 = 2x2 frags of 32x32x16.
// A (x) read as fp32, hi/lo split in-register. grid (64, 2).
// ---------------------------------------------------------------------------
__global__ __launch_bounds__(256) void gemm1_mfma_k(const float* __restrict__ X,
                                                    const __bf16* __restrict__ Wh,
                                                    const __bf16* __restrict__ Wl,
                                                    float* __restrict__ O) {
    const int tid  = threadIdx.x;
    const int lane = tid & 63;
    const int w    = tid >> 6;
    const int wm   = w >> 1;
    const int wn   = w & 1;
    const int r32  = lane & 31;
    const int kh   = lane >> 5;
    const int rowBase = blockIdx.x * 128 + wm * 64;
    const int colBase = blockIdx.y * 128 + wn * 64;

    f32x16 acc[2][2] = {};

    for (int k0 = 0; k0 < D0; k0 += 16) {
        const int koff = k0 + kh * 8;
        bf16x8 ah[2], al[2];
        #pragma unroll
        for (int i = 0; i < 2; ++i) {
            const float* px = X + (size_t)(rowBase + i * 32 + r32) * D0 + koff;
            float4 f0 = *reinterpret_cast<const float4*>(px);
            float4 f1 = *reinterpret_cast<const float4*>(px + 4);
            float f[8] = {f0.x, f0.y, f0.z, f0.w, f1.x, f1.y, f1.z, f1.w};
            #pragma unroll
            for (int e = 0; e < 8; ++e) {
                __bf16 hj = (__bf16)f[e];
                ah[i][e] = hj;
                al[i][e] = (__bf16)(f[e] - (float)hj);
            }
        }
        bf16x8 bh[2], bl[2];
        #pragma unroll
        for (int j = 0; j < 2; ++j) {
            bh[j] = *reinterpret_cast<const bf16x8*>(Wh + (size_t)(colBase + j * 32 + r32) * D0 + koff);
            bl[j] = *reinterpret_cast<const bf16x8*>(Wl + (size_t)(colBase + j * 32 + r32) * D0 + koff);
        }
        #pragma unroll
        for (int i = 0; i < 2; ++i)
            #pragma unroll
            for (int j = 0; j < 2; ++j) {
                acc[i][j] = __builtin_amdgcn_mfma_f32_32x32x16_bf16(ah[i], bh[j], acc[i][j], 0, 0, 0);
                acc[i][j] = __builtin_amdgcn_mfma_f32_32x32x16_bf16(ah[i], bl[j], acc[i][j], 0, 0, 0);
                acc[i][j] = __builtin_amdgcn_mfma_f32_32x32x16_bf16(al[i], bh[j], acc[i][j], 0, 0, 0);
            }
    }

    #pragma unroll
    for (int i = 0; i < 2; ++i)
        #pragma unroll
        for (int j = 0; j < 2; ++j)
            #pragma unroll
            for (int reg = 0; reg < 16; ++reg) {
                int r = (reg & 3) + 8 * (reg >> 2) + 4 * kh;
                O[(size_t)(rowBase + i * 32 + r) * D1 + colBase + j * 32 + r32] = acc[i][j][reg];
            }
}

// ---------------------------------------------------------------------------
// CSR build
// ---------------------------------------------------------------------------
__global__ __launch_bounds__(256) void hist_k(const int4* __restrict__ dst4,
                                              int* __restrict__ counts) {
    int i = blockIdx.x * 256 + threadIdx.x;   // grid = NE/4/256 = 256
    int4 d = dst4[i];
    atomicAdd(&counts[d.x], 1);
    atomicAdd(&counts[d.y], 1);
    atomicAdd(&counts[d.z], 1);
    atomicAdd(&counts[d.w], 1);
}

// shuffle-based scan: 256 threads x 32 counts each
__global__ __launch_bounds__(256) void scan_k(const int* __restrict__ counts,
                                              int* __restrict__ rs) {
    __shared__ int wsum[4];
    const int tid  = threadIdx.x;
    const int base = tid * 32;
    int v[32];
    int s = 0;
    #pragma unroll
    for (int j = 0; j < 8; ++j) {
        int4 q = reinterpret_cast<const int4*>(&counts[base])[j];
        v[j * 4 + 0] = q.x; v[j * 4 + 1] = q.y; v[j * 4 + 2] = q.z; v[j * 4 + 3] = q.w;
        s += q.x + q.y + q.z + q.w;
    }
    int inc = s;
    #pragma unroll
    for (int off = 1; off < 64; off <<= 1) {
        int t = __shfl_up(inc, off, 64);
        if ((tid & 63) >= off) inc += t;
    }
    if ((tid & 63) == 63) wsum[tid >> 6] = inc;
    __syncthreads();
    int wpre = 0;
    #pragma unroll
    for (int wi = 0; wi < 4; ++wi) if (wi < (tid >> 6)) wpre += wsum[wi];
    int ex = wpre + inc - s;
    #pragma unroll
    for (int j = 0; j < 32; ++j) { rs[base + j] = ex; ex += v[j]; }
    if (tid == 0) rs[NN] = NE;
}

__global__ __launch_bounds__(256) void scatter_k(const int* __restrict__ src,
                                                 const int* __restrict__ dst,
                                                 const float* __restrict__ w,
                                                 const int* __restrict__ rs,
                                                 int* __restrict__ cursor,
                                                 int* __restrict__ eps,
                                                 float* __restrict__ epw) {
    int i = blockIdx.x * 256 + threadIdx.x;
    if (i < NE) {
        int d = dst[i];
        int pos = rs[d] + atomicAdd(&cursor[d], 1);
        eps[pos] = src[i];
        epw[pos] = w[i];
    }
}

// ---------------------------------------------------------------------------
// Fused SPMM1 + relu + GEMM2, 4 rows per block, W2 staged once in LDS.
// ---------------------------------------------------------------------------
#define SF_ROWS 4
__global__ __launch_bounds__(256) void spmmfuse_k(const float* __restrict__ Hin,
                                                  const int* __restrict__ rs,
                                                  const int* __restrict__ eps,
                                                  const float* __restrict__ epw,
                                                  const float* __restrict__ W2,
                                                  float* __restrict__ H1W2) {
    __shared__ float w2s[D1 * D2];      // 64KB
    __shared__ float h1row[D1];
    __shared__ float part[4][D2];
    const int tid = threadIdx.x;
    #pragma unroll
    for (int l = 0; l < 16; ++l) {
        int idx = l * 256 + tid;
        reinterpret_cast<float4*>(w2s)[idx] = reinterpret_cast<const float4*>(W2)[idx];
    }
    const int row0 = blockIdx.x * SF_ROWS;
    const int c  = tid & 63;
    const int ks = tid >> 6;
    for (int rr = 0; rr < SF_ROWS; ++rr) {
        const int row = row0 + rr;
        const int start = rs[row], end = rs[row + 1];
        float acc = 0.f;
        for (int j = start; j < end; ++j) {
            acc += epw[j] * Hin[(size_t)eps[j] * D1 + tid];
        }
        __syncthreads();               // prev iter's h1row readers done (+W2 staging, iter 0)
        h1row[tid] = fmaxf(acc, 0.f);
        __syncthreads();
        float o = 0.f;
        #pragma unroll
        for (int k = 0; k < 64; ++k) o += h1row[ks * 64 + k] * w2s[(ks * 64 + k) * D2 + c];
        part[ks][c] = o;
        __syncthreads();
        if (tid < D2)
            H1W2[(size_t)row * D2 + tid] = part[0][tid] + part[1][tid] + part[2][tid] + part[3][tid];
    }
}

// ---------------------------------------------------------------------------
// SPMM layer 2: emits z split into hi/lo bf16 directly.
// ---------------------------------------------------------------------------
__global__ __launch_bounds__(256) void spmm64_k(const float* __restrict__ Hin,
                                                const int* __restrict__ rs,
                                                const int* __restrict__ eps,
                                                const float* __restrict__ epw,
                                                __bf16* __restrict__ Zh,
                                                __bf16* __restrict__ Zl) {
    const int row = blockIdx.x * 4 + (threadIdx.x >> 6);
    const int c = threadIdx.x & 63;
    const int start = rs[row], end = rs[row + 1];
    float acc = 0.f;
    for (int j = start; j < end; ++j) {
        acc += epw[j] * Hin[eps[j] * D2 + c];
    }
    __bf16 h = (__bf16)acc;
    Zh[row * D2 + c] = h;
    Zl[row * D2 + c] = (__bf16)(acc - (float)h);
}

// ---------------------------------------------------------------------------
// ZZT, symmetric-half: 2080 upper-triangle 128x128 tiles.
//   out = zh@zh^T + zh@zl^T + zl@zh^T
// Direct tile written coalesced NT scalar; off-diagonal mirror written via
// LDS transpose (stride 132) with NT f32x4 (native ext_vector) stores.
// ---------------------------------------------------------------------------
__global__ __launch_bounds__(256) void zzt_k(const __bf16* __restrict__ Zh,
                                             const __bf16* __restrict__ Zl,
                                             float* __restrict__ O) {
    __shared__ float tt[128][132];
    const int bid = blockIdx.x;
    int bx = (int)((sqrtf(8.f * bid + 1.f) - 1.f) * 0.5f);
    while ((bx + 1) * (bx + 2) / 2 <= bid) ++bx;
    while (bx * (bx + 1) / 2 > bid) --bx;
    const int by = bid - bx * (bx + 1) / 2;   // by <= bx
    const int R = by * 128;                   // direct tile rows
    const int C = bx * 128;                   // direct tile cols

    const int tid  = threadIdx.x;
    const int lane = tid & 63;
    const int w    = tid >> 6;
    const int wm   = w >> 1;
    const int wn   = w & 1;
    const int r32  = lane & 31;
    const int kh   = lane >> 5;
    const int rowBase = R + wm * 64;
    const int colBase = C + wn * 64;

    f32x16 acc[2][2] = {};

    #pragma unroll
    for (int kk = 0; kk < 4; ++kk) {
        const int koff = kk * 16 + kh * 8;
        bf16x8 ah0 = *reinterpret_cast<const bf16x8*>(&Zh[(rowBase +      r32) * D2 + koff]);
        bf16x8 ah1 = *reinterpret_cast<const bf16x8*>(&Zh[(rowBase + 32 + r32) * D2 + koff]);
        bf16x8 al0 = *reinterpret_cast<const bf16x8*>(&Zl[(rowBase +      r32) * D2 + koff]);
        bf16x8 al1 = *reinterpret_cast<const bf16x8*>(&Zl[(rowBase + 32 + r32) * D2 + koff]);
        bf16x8 bh0 = *reinterpret_cast<const bf16x8*>(&Zh[(colBase +      r32) * D2 + koff]);
        bf16x8 bh1 = *reinterpret_cast<const bf16x8*>(&Zh[(colBase + 32 + r32) * D2 + koff]);
        bf16x8 bl0 = *reinterpret_cast<const bf16x8*>(&Zl[(colBase +      r32) * D2 + koff]);
        bf16x8 bl1 = *reinterpret_cast<const bf16x8*>(&Zl[(colBase + 32 + r32) * D2 + koff]);

        acc[0][0] = __builtin_amdgcn_mfma_f32_32x32x16_bf16(ah0, bh0, acc[0][0], 0, 0, 0);
        acc[0][1] = __builtin_amdgcn_mfma_f32_32x32x16_bf16(ah0, bh1, acc[0][1], 0, 0, 0);
        acc[1][0] = __builtin_amdgcn_mfma_f32_32x32x16_bf16(ah1, bh0, acc[1][0], 0, 0, 0);
        acc[1][1] = __builtin_amdgcn_mfma_f32_32x32x16_bf16(ah1, bh1, acc[1][1], 0, 0, 0);

        acc[0][0] = __builtin_amdgcn_mfma_f32_32x32x16_bf16(ah0, bl0, acc[0][0], 0, 0, 0);
        acc[0][1] = __builtin_amdgcn_mfma_f32_32x32x16_bf16(ah0, bl1, acc[0][1], 0, 0, 0);
        acc[1][0] = __builtin_amdgcn_mfma_f32_32x32x16_bf16(ah1, bl0, acc[1][0], 0, 0, 0);
        acc[1][1] = __builtin_amdgcn_mfma_f32_32x32x16_bf16(ah1, bl1, acc[1][1], 0, 0, 0);

        acc[0][0] = __builtin_amdgcn_mfma_f32_32x32x16_bf16(al0, bh0, acc[0][0], 0, 0, 0);
        acc[0][1] = __builtin_amdgcn_mfma_f32_32x32x16_bf16(al0, bh1, acc[0][1], 0, 0, 0);
        acc[1][0] = __builtin_amdgcn_mfma_f32_32x32x16_bf16(al1, bh0, acc[1][0], 0, 0, 0);
        acc[1][1] = __builtin_amdgcn_mfma_f32_32x32x16_bf16(al1, bh1, acc[1][1], 0, 0, 0);
    }

    // direct tile: rows R.., cols C.. (coalesced NT scalar stores)
    #pragma unroll
    for (int i = 0; i < 2; ++i)
        #pragma unroll
        for (int j = 0; j < 2; ++j)
            #pragma unroll
            for (int reg = 0; reg < 16; ++reg) {
                int r = (reg & 3) + 8 * (reg >> 2) + 4 * kh;
                __builtin_nontemporal_store(acc[i][j][reg],
                    &O[(size_t)(R + wm * 64 + i * 32 + r) * NN + C + wn * 64 + j * 32 + r32]);
            }

    if (bx != by) {
        // stage transposed tile in LDS, then write mirror coalesced
        #pragma unroll
        for (int i = 0; i < 2; ++i)
            #pragma unroll
            for (int j = 0; j < 2; ++j)
                #pragma unroll
                for (int reg = 0; reg < 16; ++reg) {
                    int r = wm * 64 + i * 32 + (reg & 3) + 8 * (reg >> 2) + 4 * kh;
                    int cc = wn * 64 + j * 32 + r32;
                    tt[cc][r] = acc[i][j][reg];
                }
        __syncthreads();
        const int c    = tid >> 1;       // 0..127
        const int half = tid & 1;
        const float* srcp = &tt[c][half * 64];
        float* dstp = &O[(size_t)(C + c) * NN + R + half * 64];
        #pragma unroll
        for (int m = 0; m < 16; ++m) {
            f32x4 v = *reinterpret_cast<const f32x4*>(srcp + m * 4);
            __builtin_nontemporal_store(v, reinterpret_cast<f32x4*>(dstp + m * 4));
        }
    }
}

// ---------------------------------------------------------------------------
// Launch
// ---------------------------------------------------------------------------
extern "C" void kernel_launch(void* const* d_in, const int* in_sizes, int n_in,
                              void* d_out, int out_size, void* d_ws, size_t ws_size,
                              hipStream_t stream) {
    const float* x        = (const float*)d_in[0];
    const int*   edge_src = (const int*)d_in[1];
    const int*   edge_dst = (const int*)d_in[2];
    const float* edge_w   = (const float*)d_in[3];
    const float* W1       = (const float*)d_in[4];
    const float* W2       = (const float*)d_in[5];
    float* out = (float*)d_out;

    char* ws = (char*)d_ws;
    const size_t OFF_XW1  = 0;                                  // 8 MB
    const size_t OFF_H1W2 = OFF_XW1  + (size_t)NN * D1 * 4;     // 2 MB
    const size_t OFF_ZH   = OFF_H1W2 + (size_t)NN * D2 * 4;     // 1 MB
    const size_t OFF_ZL   = OFF_ZH   + (size_t)NN * D2 * 2;     // 1 MB
    const size_t OFF_WTH  = OFF_ZL   + (size_t)NN * D2 * 2;     // 256 KB
    const size_t OFF_WTL  = OFF_WTH  + (size_t)D0 * D1 * 2;     // 256 KB
    const size_t OFF_RS   = OFF_WTL  + (size_t)D0 * D1 * 2;     // (NN+1) ints
    const size_t OFF_CNT  = OFF_RS   + 33280;                   // NN ints (zeroed)
    const size_t OFF_CUR  = OFF_CNT  + (size_t)NN * 4;          // NN ints (zeroed)
    const size_t OFF_EPS  = OFF_CUR  + (size_t)NN * 4;          // NE ints
    const size_t OFF_EPW  = OFF_EPS  + (size_t)NE * 4;          // NE floats

    float*  xw1  = (float*)(ws + OFF_XW1);
    float*  h1w2 = (float*)(ws + OFF_H1W2);
    __bf16* zh   = (__bf16*)(ws + OFF_ZH);
    __bf16* zl   = (__bf16*)(ws + OFF_ZL);
    __bf16* wth  = (__bf16*)(ws + OFF_WTH);
    __bf16* wtl  = (__bf16*)(ws + OFF_WTL);
    int*    rs   = (int*)(ws + OFF_RS);
    int*    cnt  = (int*)(ws + OFF_CNT);
    int*    cur  = (int*)(ws + OFF_CUR);
    int*    eps  = (int*)(ws + OFF_EPS);
    float*  epw  = (float*)(ws + OFF_EPW);

    // prep: zero(cnt+cur) + W1 -> W1T bf16 hi/lo
    prep_k<<<16 + 128, 256, 0, stream>>>(W1, (int4*)cnt, wth, wtl);

    // GEMM1 (reads x fp32 directly, in-register hi/lo split)
    gemm1_mfma_k<<<dim3(NN / 128, D1 / 128), 256, 0, stream>>>(x, wth, wtl, xw1);

    // CSR build
    hist_k<<<NE / 4 / 256, 256, 0, stream>>>((const int4*)edge_dst, cnt);
    scan_k<<<1, 256, 0, stream>>>(cnt, rs);
    scatter_k<<<NE / 256, 256, 0, stream>>>(edge_src, edge_dst, edge_w, rs, cur, eps, epw);

    // fused SPMM1 + relu + GEMM2 (4 rows/block, W2 in LDS)
    spmmfuse_k<<<NN / SF_ROWS, 256, 0, stream>>>(xw1, rs, eps, epw, W2, h1w2);

    // SPMM2 -> zh/zl
    spmm64_k<<<NN / 4, 256, 0, stream>>>(h1w2, rs, eps, epw, zh, zl);

    // recon = z @ z^T (symmetric-half)
    zzt_k<<<2080, 256, 0, stream>>>(zh, zl, out);
}

// Round 8
// 337.340 us; speedup vs baseline: 1.8516x; 1.8516x over previous
//
#include <hip/hip_runtime.h>
#include <hip/hip_bf16.h>

// Problem constants
#define NN     8192      // nodes
#define D0     512       // x feature dim
#define D1     256       // hidden dim (W1 out)
#define D2     64        // z dim (W2 out)
#define NE     262144    // edges

typedef __attribute__((ext_vector_type(8)))  __bf16 bf16x8;
typedef __attribute__((ext_vector_type(16))) float  f32x16;

// ---------------------------------------------------------------------------
// prep_k: fused zero(cnt,cur) + convw1t (W1 -> W1T bf16 hi/lo)
// grid = 16 + 128 blocks
// ---------------------------------------------------------------------------
__global__ __launch_bounds__(256) void prep_k(const float* __restrict__ W,
                                              int4* __restrict__ zero_region,
                                              __bf16* __restrict__ Th,
                                              __bf16* __restrict__ Tl) {
    const int bid = blockIdx.x;
    const int tid = threadIdx.x;
    if (bid < 16) {
        zero_region[bid * 256 + tid] = make_int4(0, 0, 0, 0);
    } else {
        __shared__ float t[32][33];
        const int cid = bid - 16;
        const int c0 = (cid & 7) * 32;      // D1/32 = 8
        const int k0 = (cid >> 3) * 32;     // D0/32 = 16
        {
            int tr  = tid >> 3;
            int tc4 = tid & 7;
            float4 v = *reinterpret_cast<const float4*>(&W[(k0 + tr) * D1 + c0 + tc4 * 4]);
            t[tr][tc4 * 4 + 0] = v.x;
            t[tr][tc4 * 4 + 1] = v.y;
            t[tr][tc4 * 4 + 2] = v.z;
            t[tr][tc4 * 4 + 3] = v.w;
        }
        __syncthreads();
        int c  = tid >> 3;
        int kq = (tid & 7) * 4;
        __bf16 hv[4], lv[4];
        #pragma unroll
        for (int j = 0; j < 4; ++j) {
            float f = t[kq + j][c];
            hv[j] = (__bf16)f;
            lv[j] = (__bf16)(f - (float)hv[j]);
        }
        *reinterpret_cast<uint2*>(&Th[(size_t)(c0 + c) * D0 + k0 + kq]) = *reinterpret_cast<uint2*>(hv);
        *reinterpret_cast<uint2*>(&Tl[(size_t)(c0 + c) * D0 + k0 + kq]) = *reinterpret_cast<uint2*>(lv);
    }
}

// ---------------------------------------------------------------------------
// GEMM1 via bf16 MFMA hi/lo split: xw1 = x @ W1
// 128x128 block, 4 waves (2x2), wave = 64x64 = 2x2 frags of 32x32x16.
// A (x) read as fp32, hi/lo split in-register. grid (64, 2).
// ---------------------------------------------------------------------------
__global__ __launch_bounds__(256) void gemm1_mfma_k(const float* __restrict__ X,
                                                    const __bf16* __restrict__ Wh,
                                                    const __bf16* __restrict__ Wl,
                                                    float* __restrict__ O) {
    const int tid  = threadIdx.x;
    const int lane = tid & 63;
    const int w    = tid >> 6;
    const int wm   = w >> 1;
    const int wn   = w & 1;
    const int r32  = lane & 31;
    const int kh   = lane >> 5;
    const int rowBase = blockIdx.x * 128 + wm * 64;
    const int colBase = blockIdx.y * 128 + wn * 64;

    f32x16 acc[2][2] = {};

    for (int k0 = 0; k0 < D0; k0 += 16) {
        const int koff = k0 + kh * 8;
        bf16x8 ah[2], al[2];
        #pragma unroll
        for (int i = 0; i < 2; ++i) {
            const float* px = X + (size_t)(rowBase + i * 32 + r32) * D0 + koff;
            float4 f0 = *reinterpret_cast<const float4*>(px);
            float4 f1 = *reinterpret_cast<const float4*>(px + 4);
            float f[8] = {f0.x, f0.y, f0.z, f0.w, f1.x, f1.y, f1.z, f1.w};
            #pragma unroll
            for (int e = 0; e < 8; ++e) {
                __bf16 hj = (__bf16)f[e];
                ah[i][e] = hj;
                al[i][e] = (__bf16)(f[e] - (float)hj);
            }
        }
        bf16x8 bh[2], bl[2];
        #pragma unroll
        for (int j = 0; j < 2; ++j) {
            bh[j] = *reinterpret_cast<const bf16x8*>(Wh + (size_t)(colBase + j * 32 + r32) * D0 + koff);
            bl[j] = *reinterpret_cast<const bf16x8*>(Wl + (size_t)(colBase + j * 32 + r32) * D0 + koff);
        }
        #pragma unroll
        for (int i = 0; i < 2; ++i)
            #pragma unroll
            for (int j = 0; j < 2; ++j) {
                acc[i][j] = __builtin_amdgcn_mfma_f32_32x32x16_bf16(ah[i], bh[j], acc[i][j], 0, 0, 0);
                acc[i][j] = __builtin_amdgcn_mfma_f32_32x32x16_bf16(ah[i], bl[j], acc[i][j], 0, 0, 0);
                acc[i][j] = __builtin_amdgcn_mfma_f32_32x32x16_bf16(al[i], bh[j], acc[i][j], 0, 0, 0);
            }
    }

    #pragma unroll
    for (int i = 0; i < 2; ++i)
        #pragma unroll
        for (int j = 0; j < 2; ++j)
            #pragma unroll
            for (int reg = 0; reg < 16; ++reg) {
                int r = (reg & 3) + 8 * (reg >> 2) + 4 * kh;
                O[(size_t)(rowBase + i * 32 + r) * D1 + colBase + j * 32 + r32] = acc[i][j][reg];
            }
}

// ---------------------------------------------------------------------------
// CSR build
// ---------------------------------------------------------------------------
__global__ __launch_bounds__(256) void hist_k(const int4* __restrict__ dst4,
                                              int* __restrict__ counts) {
    int i = blockIdx.x * 256 + threadIdx.x;   // grid = NE/4/256 = 256
    int4 d = dst4[i];
    atomicAdd(&counts[d.x], 1);
    atomicAdd(&counts[d.y], 1);
    atomicAdd(&counts[d.z], 1);
    atomicAdd(&counts[d.w], 1);
}

// shuffle-based scan: 256 threads x 32 counts each
__global__ __launch_bounds__(256) void scan_k(const int* __restrict__ counts,
                                              int* __restrict__ rs) {
    __shared__ int wsum[4];
    const int tid  = threadIdx.x;
    const int base = tid * 32;
    int v[32];
    int s = 0;
    #pragma unroll
    for (int j = 0; j < 8; ++j) {
        int4 q = reinterpret_cast<const int4*>(&counts[base])[j];
        v[j * 4 + 0] = q.x; v[j * 4 + 1] = q.y; v[j * 4 + 2] = q.z; v[j * 4 + 3] = q.w;
        s += q.x + q.y + q.z + q.w;
    }
    int inc = s;
    #pragma unroll
    for (int off = 1; off < 64; off <<= 1) {
        int t = __shfl_up(inc, off, 64);
        if ((tid & 63) >= off) inc += t;
    }
    if ((tid & 63) == 63) wsum[tid >> 6] = inc;
    __syncthreads();
    int wpre = 0;
    #pragma unroll
    for (int wi = 0; wi < 4; ++wi) if (wi < (tid >> 6)) wpre += wsum[wi];
    int ex = wpre + inc - s;
    #pragma unroll
    for (int j = 0; j < 32; ++j) { rs[base + j] = ex; ex += v[j]; }
    if (tid == 0) rs[NN] = NE;
}

__global__ __launch_bounds__(256) void scatter_k(const int* __restrict__ src,
                                                 const int* __restrict__ dst,
                                                 const float* __restrict__ w,
                                                 const int* __restrict__ rs,
                                                 int* __restrict__ cursor,
                                                 int* __restrict__ eps,
                                                 float* __restrict__ epw) {
    int i = blockIdx.x * 256 + threadIdx.x;
    if (i < NE) {
        int d = dst[i];
        int pos = rs[d] + atomicAdd(&cursor[d], 1);
        eps[pos] = src[i];
        epw[pos] = w[i];
    }
}

// ---------------------------------------------------------------------------
// Fused SPMM1 + relu + GEMM2, 4 rows per block, W2 staged once in LDS.
// ---------------------------------------------------------------------------
#define SF_ROWS 4
__global__ __launch_bounds__(256) void spmmfuse_k(const float* __restrict__ Hin,
                                                  const int* __restrict__ rs,
                                                  const int* __restrict__ eps,
                                                  const float* __restrict__ epw,
                                                  const float* __restrict__ W2,
                                                  float* __restrict__ H1W2) {
    __shared__ float w2s[D1 * D2];      // 64KB
    __shared__ float h1row[D1];
    __shared__ float part[4][D2];
    const int tid = threadIdx.x;
    #pragma unroll
    for (int l = 0; l < 16; ++l) {
        int idx = l * 256 + tid;
        reinterpret_cast<float4*>(w2s)[idx] = reinterpret_cast<const float4*>(W2)[idx];
    }
    const int row0 = blockIdx.x * SF_ROWS;
    const int c  = tid & 63;
    const int ks = tid >> 6;
    for (int rr = 0; rr < SF_ROWS; ++rr) {
        const int row = row0 + rr;
        const int start = rs[row], end = rs[row + 1];
        float acc = 0.f;
        for (int j = start; j < end; ++j) {
            acc += epw[j] * Hin[(size_t)eps[j] * D1 + tid];
        }
        __syncthreads();               // prev iter's h1row readers done (+W2 staging, iter 0)
        h1row[tid] = fmaxf(acc, 0.f);
        __syncthreads();
        float o = 0.f;
        #pragma unroll
        for (int k = 0; k < 64; ++k) o += h1row[ks * 64 + k] * w2s[(ks * 64 + k) * D2 + c];
        part[ks][c] = o;
        __syncthreads();
        if (tid < D2)
            H1W2[(size_t)row * D2 + tid] = part[0][tid] + part[1][tid] + part[2][tid] + part[3][tid];
    }
}

// ---------------------------------------------------------------------------
// SPMM layer 2: emits z split into hi/lo bf16 directly.
// ---------------------------------------------------------------------------
__global__ __launch_bounds__(256) void spmm64_k(const float* __restrict__ Hin,
                                                const int* __restrict__ rs,
                                                const int* __restrict__ eps,
                                                const float* __restrict__ epw,
                                                __bf16* __restrict__ Zh,
                                                __bf16* __restrict__ Zl) {
    const int row = blockIdx.x * 4 + (threadIdx.x >> 6);
    const int c = threadIdx.x & 63;
    const int start = rs[row], end = rs[row + 1];
    float acc = 0.f;
    for (int j = start; j < end; ++j) {
        acc += epw[j] * Hin[eps[j] * D2 + c];
    }
    __bf16 h = (__bf16)acc;
    Zh[row * D2 + c] = h;
    Zl[row * D2 + c] = (__bf16)(acc - (float)h);
}

// ---------------------------------------------------------------------------
// ZZT via bf16 MFMA hi/lo split — proven R2 form:
// full 4096-block grid, no LDS, no symmetry trick, PLAIN cached stores.
// (R6's symmetric-half + NT-store variant caused 8.2GB HBM fetch: NT write
// stream evicted the L2-resident zh/zl operands; 385us vs ~55us.)
//   out = zh@zh^T + zh@zl^T + zl@zh^T
// ---------------------------------------------------------------------------
__global__ __launch_bounds__(256) void zzt_k(const __bf16* __restrict__ Zh,
                                             const __bf16* __restrict__ Zl,
                                             float* __restrict__ O) {
    const int tid  = threadIdx.x;
    const int lane = tid & 63;
    const int w    = tid >> 6;
    const int wm   = w >> 1;
    const int wn   = w & 1;
    const int r32  = lane & 31;
    const int kh   = lane >> 5;
    const int rowBase = blockIdx.y * 128 + wm * 64;
    const int colBase = blockIdx.x * 128 + wn * 64;

    f32x16 acc[2][2] = {};

    #pragma unroll
    for (int kk = 0; kk < 4; ++kk) {
        const int koff = kk * 16 + kh * 8;
        bf16x8 ah0 = *reinterpret_cast<const bf16x8*>(&Zh[(rowBase +      r32) * D2 + koff]);
        bf16x8 ah1 = *reinterpret_cast<const bf16x8*>(&Zh[(rowBase + 32 + r32) * D2 + koff]);
        bf16x8 al0 = *reinterpret_cast<const bf16x8*>(&Zl[(rowBase +      r32) * D2 + koff]);
        bf16x8 al1 = *reinterpret_cast<const bf16x8*>(&Zl[(rowBase + 32 + r32) * D2 + koff]);
        bf16x8 bh0 = *reinterpret_cast<const bf16x8*>(&Zh[(colBase +      r32) * D2 + koff]);
        bf16x8 bh1 = *reinterpret_cast<const bf16x8*>(&Zh[(colBase + 32 + r32) * D2 + koff]);
        bf16x8 bl0 = *reinterpret_cast<const bf16x8*>(&Zl[(colBase +      r32) * D2 + koff]);
        bf16x8 bl1 = *reinterpret_cast<const bf16x8*>(&Zl[(colBase + 32 + r32) * D2 + koff]);

        acc[0][0] = __builtin_amdgcn_mfma_f32_32x32x16_bf16(ah0, bh0, acc[0][0], 0, 0, 0);
        acc[0][1] = __builtin_amdgcn_mfma_f32_32x32x16_bf16(ah0, bh1, acc[0][1], 0, 0, 0);
        acc[1][0] = __builtin_amdgcn_mfma_f32_32x32x16_bf16(ah1, bh0, acc[1][0], 0, 0, 0);
        acc[1][1] = __builtin_amdgcn_mfma_f32_32x32x16_bf16(ah1, bh1, acc[1][1], 0, 0, 0);

        acc[0][0] = __builtin_amdgcn_mfma_f32_32x32x16_bf16(ah0, bl0, acc[0][0], 0, 0, 0);
        acc[0][1] = __builtin_amdgcn_mfma_f32_32x32x16_bf16(ah0, bl1, acc[0][1], 0, 0, 0);
        acc[1][0] = __builtin_amdgcn_mfma_f32_32x32x16_bf16(ah1, bl0, acc[1][0], 0, 0, 0);
        acc[1][1] = __builtin_amdgcn_mfma_f32_32x32x16_bf16(ah1, bl1, acc[1][1], 0, 0, 0);

        acc[0][0] = __builtin_amdgcn_mfma_f32_32x32x16_bf16(al0, bh0, acc[0][0], 0, 0, 0);
        acc[0][1] = __builtin_amdgcn_mfma_f32_32x32x16_bf16(al0, bh1, acc[0][1], 0, 0, 0);
        acc[1][0] = __builtin_amdgcn_mfma_f32_32x32x16_bf16(al1, bh0, acc[1][0], 0, 0, 0);
        acc[1][1] = __builtin_amdgcn_mfma_f32_32x32x16_bf16(al1, bh1, acc[1][1], 0, 0, 0);
    }

    #pragma unroll
    for (int i = 0; i < 2; ++i)
        #pragma unroll
        for (int j = 0; j < 2; ++j)
            #pragma unroll
            for (int reg = 0; reg < 16; ++reg) {
                int r = (reg & 3) + 8 * (reg >> 2) + 4 * kh;
                O[(size_t)(rowBase + i * 32 + r) * NN + colBase + j * 32 + r32] = acc[i][j][reg];
            }
}

// ---------------------------------------------------------------------------
// Launch
// ---------------------------------------------------------------------------
extern "C" void kernel_launch(void* const* d_in, const int* in_sizes, int n_in,
                              void* d_out, int out_size, void* d_ws, size_t ws_size,
                              hipStream_t stream) {
    const float* x        = (const float*)d_in[0];
    const int*   edge_src = (const int*)d_in[1];
    const int*   edge_dst = (const int*)d_in[2];
    const float* edge_w   = (const float*)d_in[3];
    const float* W1       = (const float*)d_in[4];
    const float* W2       = (const float*)d_in[5];
    float* out = (float*)d_out;

    char* ws = (char*)d_ws;
    const size_t OFF_XW1  = 0;                                  // 8 MB
    const size_t OFF_H1W2 = OFF_XW1  + (size_t)NN * D1 * 4;     // 2 MB
    const size_t OFF_ZH   = OFF_H1W2 + (size_t)NN * D2 * 4;     // 1 MB
    const size_t OFF_ZL   = OFF_ZH   + (size_t)NN * D2 * 2;     // 1 MB
    const size_t OFF_WTH  = OFF_ZL   + (size_t)NN * D2 * 2;     // 256 KB
    const size_t OFF_WTL  = OFF_WTH  + (size_t)D0 * D1 * 2;     // 256 KB
    const size_t OFF_RS   = OFF_WTL  + (size_t)D0 * D1 * 2;     // (NN+1) ints
    const size_t OFF_CNT  = OFF_RS   + 33280;                   // NN ints (zeroed)
    const size_t OFF_CUR  = OFF_CNT  + (size_t)NN * 4;          // NN ints (zeroed)
    const size_t OFF_EPS  = OFF_CUR  + (size_t)NN * 4;          // NE ints
    const size_t OFF_EPW  = OFF_EPS  + (size_t)NE * 4;          // NE floats

    float*  xw1  = (float*)(ws + OFF_XW1);
    float*  h1w2 = (float*)(ws + OFF_H1W2);
    __bf16* zh   = (__bf16*)(ws + OFF_ZH);
    __bf16* zl   = (__bf16*)(ws + OFF_ZL);
    __bf16* wth  = (__bf16*)(ws + OFF_WTH);
    __bf16* wtl  = (__bf16*)(ws + OFF_WTL);
    int*    rs   = (int*)(ws + OFF_RS);
    int*    cnt  = (int*)(ws + OFF_CNT);
    int*    cur  = (int*)(ws + OFF_CUR);
    int*    eps  = (int*)(ws + OFF_EPS);
    float*  epw  = (float*)(ws + OFF_EPW);

    // prep: zero(cnt+cur) + W1 -> W1T bf16 hi/lo
    prep_k<<<16 + 128, 256, 0, stream>>>(W1, (int4*)cnt, wth, wtl);

    // GEMM1 (reads x fp32 directly, in-register hi/lo split)
    gemm1_mfma_k<<<dim3(NN / 128, D1 / 128), 256, 0, stream>>>(x, wth, wtl, xw1);

    // CSR build
    hist_k<<<NE / 4 / 256, 256, 0, stream>>>((const int4*)edge_dst, cnt);
    scan_k<<<1, 256, 0, stream>>>(cnt, rs);
    scatter_k<<<NE / 256, 256, 0, stream>>>(edge_src, edge_dst, edge_w, rs, cur, eps, epw);

    // fused SPMM1 + relu + GEMM2 (4 rows/block, W2 in LDS)
    spmmfuse_k<<<NN / SF_ROWS, 256, 0, stream>>>(xw1, rs, eps, epw, W2, h1w2);

    // SPMM2 -> zh/zl
    spmm64_k<<<NN / 4, 256, 0, stream>>>(h1w2, rs, eps, epw, zh, zl);

    // recon = z @ z^T (full grid, plain stores)
    zzt_k<<<dim3(NN / 128, NN / 128), 256, 0, stream>>>(zh, zl, out);
}

// Round 9
// 246.498 us; speedup vs baseline: 2.5340x; 1.3685x over previous
//
#include <hip/hip_runtime.h>
#include <hip/hip_bf16.h>

// Problem constants
#define NN     8192      // nodes
#define D0     512       // x feature dim
#define D1     256       // hidden dim (W1 out)
#define D2     64        // z dim (W2 out)
#define NE     262144    // edges

typedef __attribute__((ext_vector_type(8)))  __bf16 bf16x8;
typedef __attribute__((ext_vector_type(16))) float  f32x16;

// ---------------------------------------------------------------------------
// prep_k: fused zero(cnt,cur) + convw1t (W1 -> W1T bf16 hi/lo)
// grid = 16 + 128 blocks
// ---------------------------------------------------------------------------
__global__ __launch_bounds__(256) void prep_k(const float* __restrict__ W,
                                              int4* __restrict__ zero_region,
                                              __bf16* __restrict__ Th,
                                              __bf16* __restrict__ Tl) {
    const int bid = blockIdx.x;
    const int tid = threadIdx.x;
    if (bid < 16) {
        zero_region[bid * 256 + tid] = make_int4(0, 0, 0, 0);
    } else {
        __shared__ float t[32][33];
        const int cid = bid - 16;
        const int c0 = (cid & 7) * 32;      // D1/32 = 8
        const int k0 = (cid >> 3) * 32;     // D0/32 = 16
        {
            int tr  = tid >> 3;
            int tc4 = tid & 7;
            float4 v = *reinterpret_cast<const float4*>(&W[(k0 + tr) * D1 + c0 + tc4 * 4]);
            t[tr][tc4 * 4 + 0] = v.x;
            t[tr][tc4 * 4 + 1] = v.y;
            t[tr][tc4 * 4 + 2] = v.z;
            t[tr][tc4 * 4 + 3] = v.w;
        }
        __syncthreads();
        int c  = tid >> 3;
        int kq = (tid & 7) * 4;
        __bf16 hv[4], lv[4];
        #pragma unroll
        for (int j = 0; j < 4; ++j) {
            float f = t[kq + j][c];
            hv[j] = (__bf16)f;
            lv[j] = (__bf16)(f - (float)hv[j]);
        }
        *reinterpret_cast<uint2*>(&Th[(size_t)(c0 + c) * D0 + k0 + kq]) = *reinterpret_cast<uint2*>(hv);
        *reinterpret_cast<uint2*>(&Tl[(size_t)(c0 + c) * D0 + k0 + kq]) = *reinterpret_cast<uint2*>(lv);
    }
}

// ---------------------------------------------------------------------------
// GEMM1 via bf16 MFMA hi/lo split: xw1 = x @ W1
// 128x128 block, 4 waves (2x2), wave = 64x64 = 2x2 frags of 32x32x16.
// A (x) read as fp32, hi/lo split in-register. grid (64, 2).
// ---------------------------------------------------------------------------
__global__ __launch_bounds__(256) void gemm1_mfma_k(const float* __restrict__ X,
                                                    const __bf16* __restrict__ Wh,
                                                    const __bf16* __restrict__ Wl,
                                                    float* __restrict__ O) {
    const int tid  = threadIdx.x;
    const int lane = tid & 63;
    const int w    = tid >> 6;
    const int wm   = w >> 1;
    const int wn   = w & 1;
    const int r32  = lane & 31;
    const int kh   = lane >> 5;
    const int rowBase = blockIdx.x * 128 + wm * 64;
    const int colBase = blockIdx.y * 128 + wn * 64;

    f32x16 acc[2][2] = {};

    for (int k0 = 0; k0 < D0; k0 += 16) {
        const int koff = k0 + kh * 8;
        bf16x8 ah[2], al[2];
        #pragma unroll
        for (int i = 0; i < 2; ++i) {
            const float* px = X + (size_t)(rowBase + i * 32 + r32) * D0 + koff;
            float4 f0 = *reinterpret_cast<const float4*>(px);
            float4 f1 = *reinterpret_cast<const float4*>(px + 4);
            float f[8] = {f0.x, f0.y, f0.z, f0.w, f1.x, f1.y, f1.z, f1.w};
            #pragma unroll
            for (int e = 0; e < 8; ++e) {
                __bf16 hj = (__bf16)f[e];
                ah[i][e] = hj;
                al[i][e] = (__bf16)(f[e] - (float)hj);
            }
        }
        bf16x8 bh[2], bl[2];
        #pragma unroll
        for (int j = 0; j < 2; ++j) {
            bh[j] = *reinterpret_cast<const bf16x8*>(Wh + (size_t)(colBase + j * 32 + r32) * D0 + koff);
            bl[j] = *reinterpret_cast<const bf16x8*>(Wl + (size_t)(colBase + j * 32 + r32) * D0 + koff);
        }
        #pragma unroll
        for (int i = 0; i < 2; ++i)
            #pragma unroll
            for (int j = 0; j < 2; ++j) {
                acc[i][j] = __builtin_amdgcn_mfma_f32_32x32x16_bf16(ah[i], bh[j], acc[i][j], 0, 0, 0);
                acc[i][j] = __builtin_amdgcn_mfma_f32_32x32x16_bf16(ah[i], bl[j], acc[i][j], 0, 0, 0);
                acc[i][j] = __builtin_amdgcn_mfma_f32_32x32x16_bf16(al[i], bh[j], acc[i][j], 0, 0, 0);
            }
    }

    #pragma unroll
    for (int i = 0; i < 2; ++i)
        #pragma unroll
        for (int j = 0; j < 2; ++j)
            #pragma unroll
            for (int reg = 0; reg < 16; ++reg) {
                int r = (reg & 3) + 8 * (reg >> 2) + 4 * kh;
                O[(size_t)(rowBase + i * 32 + r) * D1 + colBase + j * 32 + r32] = acc[i][j][reg];
            }
}

// ---------------------------------------------------------------------------
// CSR build
// ---------------------------------------------------------------------------
__global__ __launch_bounds__(256) void hist_k(const int4* __restrict__ dst4,
                                              int* __restrict__ counts) {
    int i = blockIdx.x * 256 + threadIdx.x;   // grid = NE/4/256 = 256
    int4 d = dst4[i];
    atomicAdd(&counts[d.x], 1);
    atomicAdd(&counts[d.y], 1);
    atomicAdd(&counts[d.z], 1);
    atomicAdd(&counts[d.w], 1);
}

// shuffle-based scan: 256 threads x 32 counts each
__global__ __launch_bounds__(256) void scan_k(const int* __restrict__ counts,
                                              int* __restrict__ rs) {
    __shared__ int wsum[4];
    const int tid  = threadIdx.x;
    const int base = tid * 32;
    int v[32];
    int s = 0;
    #pragma unroll
    for (int j = 0; j < 8; ++j) {
        int4 q = reinterpret_cast<const int4*>(&counts[base])[j];
        v[j * 4 + 0] = q.x; v[j * 4 + 1] = q.y; v[j * 4 + 2] = q.z; v[j * 4 + 3] = q.w;
        s += q.x + q.y + q.z + q.w;
    }
    int inc = s;
    #pragma unroll
    for (int off = 1; off < 64; off <<= 1) {
        int t = __shfl_up(inc, off, 64);
        if ((tid & 63) >= off) inc += t;
    }
    if ((tid & 63) == 63) wsum[tid >> 6] = inc;
    __syncthreads();
    int wpre = 0;
    #pragma unroll
    for (int wi = 0; wi < 4; ++wi) if (wi < (tid >> 6)) wpre += wsum[wi];
    int ex = wpre + inc - s;
    #pragma unroll
    for (int j = 0; j < 32; ++j) { rs[base + j] = ex; ex += v[j]; }
    if (tid == 0) rs[NN] = NE;
}

__global__ __launch_bounds__(256) void scatter_k(const int* __restrict__ src,
                                                 const int* __restrict__ dst,
                                                 const float* __restrict__ w,
                                                 const int* __restrict__ rs,
                                                 int* __restrict__ cursor,
                                                 int* __restrict__ eps,
                                                 float* __restrict__ epw) {
    int i = blockIdx.x * 256 + threadIdx.x;
    if (i < NE) {
        int d = dst[i];
        int pos = rs[d] + atomicAdd(&cursor[d], 1);
        eps[pos] = src[i];
        epw[pos] = w[i];
    }
}

// ---------------------------------------------------------------------------
// Fused SPMM1 + relu + GEMM2 — LIGHT form (R4-proven):
// one row per 256-thread block, only h1row (1KB) in LDS, W2 from L2.
// (R8 counters: the 64KB W2-in-LDS variant -> 2 blocks/CU, 20% occupancy,
// latency-bound gather at 0.5TB/s, 158us. Occupancy is the lever here.)
// ---------------------------------------------------------------------------
__global__ __launch_bounds__(256) void spmmfuse_k(const float* __restrict__ Hin,
                                                  const int* __restrict__ rs,
                                                  const int* __restrict__ eps,
                                                  const float* __restrict__ epw,
                                                  const float* __restrict__ W2,
                                                  float* __restrict__ H1W2) {
    __shared__ float h1row[D1];
    const int row = blockIdx.x;
    const int tid = threadIdx.x;
    const int start = rs[row], end = rs[row + 1];
    float acc = 0.f;
    for (int j = start; j < end; ++j) {
        acc += epw[j] * Hin[(size_t)eps[j] * D1 + tid];
    }
    h1row[tid] = fmaxf(acc, 0.f);
    __syncthreads();
    if (tid < D2) {
        float o = 0.f;
        #pragma unroll 16
        for (int k = 0; k < D1; ++k) o += h1row[k] * W2[k * D2 + tid];
        H1W2[(size_t)row * D2 + tid] = o;
    }
}

// ---------------------------------------------------------------------------
// SPMM layer 2: emits z split into hi/lo bf16 directly.
// ---------------------------------------------------------------------------
__global__ __launch_bounds__(256) void spmm64_k(const float* __restrict__ Hin,
                                                const int* __restrict__ rs,
                                                const int* __restrict__ eps,
                                                const float* __restrict__ epw,
                                                __bf16* __restrict__ Zh,
                                                __bf16* __restrict__ Zl) {
    const int row = blockIdx.x * 4 + (threadIdx.x >> 6);
    const int c = threadIdx.x & 63;
    const int start = rs[row], end = rs[row + 1];
    float acc = 0.f;
    for (int j = start; j < end; ++j) {
        acc += epw[j] * Hin[eps[j] * D2 + c];
    }
    __bf16 h = (__bf16)acc;
    Zh[row * D2 + c] = h;
    Zl[row * D2 + c] = (__bf16)(acc - (float)h);
}

// ---------------------------------------------------------------------------
// ZZT via bf16 MFMA hi/lo split — proven R2 form:
// full 4096-block grid, no LDS, plain cached stores.
//   out = zh@zh^T + zh@zl^T + zl@zh^T
// ---------------------------------------------------------------------------
__global__ __launch_bounds__(256) void zzt_k(const __bf16* __restrict__ Zh,
                                             const __bf16* __restrict__ Zl,
                                             float* __restrict__ O) {
    const int tid  = threadIdx.x;
    const int lane = tid & 63;
    const int w    = tid >> 6;
    const int wm   = w >> 1;
    const int wn   = w & 1;
    const int r32  = lane & 31;
    const int kh   = lane >> 5;
    const int rowBase = blockIdx.y * 128 + wm * 64;
    const int colBase = blockIdx.x * 128 + wn * 64;

    f32x16 acc[2][2] = {};

    #pragma unroll
    for (int kk = 0; kk < 4; ++kk) {
        const int koff = kk * 16 + kh * 8;
        bf16x8 ah0 = *reinterpret_cast<const bf16x8*>(&Zh[(rowBase +      r32) * D2 + koff]);
        bf16x8 ah1 = *reinterpret_cast<const bf16x8*>(&Zh[(rowBase + 32 + r32) * D2 + koff]);
        bf16x8 al0 = *reinterpret_cast<const bf16x8*>(&Zl[(rowBase +      r32) * D2 + koff]);
        bf16x8 al1 = *reinterpret_cast<const bf16x8*>(&Zl[(rowBase + 32 + r32) * D2 + koff]);
        bf16x8 bh0 = *reinterpret_cast<const bf16x8*>(&Zh[(colBase +      r32) * D2 + koff]);
        bf16x8 bh1 = *reinterpret_cast<const bf16x8*>(&Zh[(colBase + 32 + r32) * D2 + koff]);
        bf16x8 bl0 = *reinterpret_cast<const bf16x8*>(&Zl[(colBase +      r32) * D2 + koff]);
        bf16x8 bl1 = *reinterpret_cast<const bf16x8*>(&Zl[(colBase + 32 + r32) * D2 + koff]);

        acc[0][0] = __builtin_amdgcn_mfma_f32_32x32x16_bf16(ah0, bh0, acc[0][0], 0, 0, 0);
        acc[0][1] = __builtin_amdgcn_mfma_f32_32x32x16_bf16(ah0, bh1, acc[0][1], 0, 0, 0);
        acc[1][0] = __builtin_amdgcn_mfma_f32_32x32x16_bf16(ah1, bh0, acc[1][0], 0, 0, 0);
        acc[1][1] = __builtin_amdgcn_mfma_f32_32x32x16_bf16(ah1, bh1, acc[1][1], 0, 0, 0);

        acc[0][0] = __builtin_amdgcn_mfma_f32_32x32x16_bf16(ah0, bl0, acc[0][0], 0, 0, 0);
        acc[0][1] = __builtin_amdgcn_mfma_f32_32x32x16_bf16(ah0, bl1, acc[0][1], 0, 0, 0);
        acc[1][0] = __builtin_amdgcn_mfma_f32_32x32x16_bf16(ah1, bl0, acc[1][0], 0, 0, 0);
        acc[1][1] = __builtin_amdgcn_mfma_f32_32x32x16_bf16(ah1, bl1, acc[1][1], 0, 0, 0);

        acc[0][0] = __builtin_amdgcn_mfma_f32_32x32x16_bf16(al0, bh0, acc[0][0], 0, 0, 0);
        acc[0][1] = __builtin_amdgcn_mfma_f32_32x32x16_bf16(al0, bh1, acc[0][1], 0, 0, 0);
        acc[1][0] = __builtin_amdgcn_mfma_f32_32x32x16_bf16(al1, bh0, acc[1][0], 0, 0, 0);
        acc[1][1] = __builtin_amdgcn_mfma_f32_32x32x16_bf16(al1, bh1, acc[1][1], 0, 0, 0);
    }

    #pragma unroll
    for (int i = 0; i < 2; ++i)
        #pragma unroll
        for (int j = 0; j < 2; ++j)
            #pragma unroll
            for (int reg = 0; reg < 16; ++reg) {
                int r = (reg & 3) + 8 * (reg >> 2) + 4 * kh;
                O[(size_t)(rowBase + i * 32 + r) * NN + colBase + j * 32 + r32] = acc[i][j][reg];
            }
}

// ---------------------------------------------------------------------------
// Launch
// ---------------------------------------------------------------------------
extern "C" void kernel_launch(void* const* d_in, const int* in_sizes, int n_in,
                              void* d_out, int out_size, void* d_ws, size_t ws_size,
                              hipStream_t stream) {
    const float* x        = (const float*)d_in[0];
    const int*   edge_src = (const int*)d_in[1];
    const int*   edge_dst = (const int*)d_in[2];
    const float* edge_w   = (const float*)d_in[3];
    const float* W1       = (const float*)d_in[4];
    const float* W2       = (const float*)d_in[5];
    float* out = (float*)d_out;

    char* ws = (char*)d_ws;
    const size_t OFF_XW1  = 0;                                  // 8 MB
    const size_t OFF_H1W2 = OFF_XW1  + (size_t)NN * D1 * 4;     // 2 MB
    const size_t OFF_ZH   = OFF_H1W2 + (size_t)NN * D2 * 4;     // 1 MB
    const size_t OFF_ZL   = OFF_ZH   + (size_t)NN * D2 * 2;     // 1 MB
    const size_t OFF_WTH  = OFF_ZL   + (size_t)NN * D2 * 2;     // 256 KB
    const size_t OFF_WTL  = OFF_WTH  + (size_t)D0 * D1 * 2;     // 256 KB
    const size_t OFF_RS   = OFF_WTL  + (size_t)D0 * D1 * 2;     // (NN+1) ints
    const size_t OFF_CNT  = OFF_RS   + 33280;                   // NN ints (zeroed)
    const size_t OFF_CUR  = OFF_CNT  + (size_t)NN * 4;          // NN ints (zeroed)
    const size_t OFF_EPS  = OFF_CUR  + (size_t)NN * 4;          // NE ints
    const size_t OFF_EPW  = OFF_EPS  + (size_t)NE * 4;          // NE floats

    float*  xw1  = (float*)(ws + OFF_XW1);
    float*  h1w2 = (float*)(ws + OFF_H1W2);
    __bf16* zh   = (__bf16*)(ws + OFF_ZH);
    __bf16* zl   = (__bf16*)(ws + OFF_ZL);
    __bf16* wth  = (__bf16*)(ws + OFF_WTH);
    __bf16* wtl  = (__bf16*)(ws + OFF_WTL);
    int*    rs   = (int*)(ws + OFF_RS);
    int*    cnt  = (int*)(ws + OFF_CNT);
    int*    cur  = (int*)(ws + OFF_CUR);
    int*    eps  = (int*)(ws + OFF_EPS);
    float*  epw  = (float*)(ws + OFF_EPW);

    // prep: zero(cnt+cur) + W1 -> W1T bf16 hi/lo
    prep_k<<<16 + 128, 256, 0, stream>>>(W1, (int4*)cnt, wth, wtl);

    // GEMM1 (reads x fp32 directly, in-register hi/lo split)
    gemm1_mfma_k<<<dim3(NN / 128, D1 / 128), 256, 0, stream>>>(x, wth, wtl, xw1);

    // CSR build
    hist_k<<<NE / 4 / 256, 256, 0, stream>>>((const int4*)edge_dst, cnt);
    scan_k<<<1, 256, 0, stream>>>(cnt, rs);
    scatter_k<<<NE / 256, 256, 0, stream>>>(edge_src, edge_dst, edge_w, rs, cur, eps, epw);

    // fused SPMM1 + relu + GEMM2 (light: 1 row/block, W2 from L2)
    spmmfuse_k<<<NN, 256, 0, stream>>>(xw1, rs, eps, epw, W2, h1w2);

    // SPMM2 -> zh/zl
    spmm64_k<<<NN / 4, 256, 0, stream>>>(h1w2, rs, eps, epw, zh, zl);

    // recon = z @ z^T (full grid, plain stores)
    zzt_k<<<dim3(NN / 128, NN / 128), 256, 0, stream>>>(zh, zl, out);
}

// Round 10
// 231.896 us; speedup vs baseline: 2.6935x; 1.0630x over previous
//
#include <hip/hip_runtime.h>
#include <hip/hip_bf16.h>

// Problem constants
#define NN     8192      // nodes
#define D0     512       // x feature dim
#define D1     256       // hidden dim (W1 out)
#define D2     64        // z dim (W2 out)
#define NE     262144    // edges

typedef __attribute__((ext_vector_type(8)))  __bf16 bf16x8;
typedef __attribute__((ext_vector_type(16))) float  f32x16;

// ---------------------------------------------------------------------------
// prep_k: fused zero(cnt,cur) + convw1t (W1 -> W1T bf16 hi/lo)
// grid = 16 + 128 blocks
// ---------------------------------------------------------------------------
__global__ __launch_bounds__(256) void prep_k(const float* __restrict__ W,
                                              int4* __restrict__ zero_region,
                                              __bf16* __restrict__ Th,
                                              __bf16* __restrict__ Tl) {
    const int bid = blockIdx.x;
    const int tid = threadIdx.x;
    if (bid < 16) {
        zero_region[bid * 256 + tid] = make_int4(0, 0, 0, 0);
    } else {
        __shared__ float t[32][33];
        const int cid = bid - 16;
        const int c0 = (cid & 7) * 32;      // D1/32 = 8
        const int k0 = (cid >> 3) * 32;     // D0/32 = 16
        {
            int tr  = tid >> 3;
            int tc4 = tid & 7;
            float4 v = *reinterpret_cast<const float4*>(&W[(k0 + tr) * D1 + c0 + tc4 * 4]);
            t[tr][tc4 * 4 + 0] = v.x;
            t[tr][tc4 * 4 + 1] = v.y;
            t[tr][tc4 * 4 + 2] = v.z;
            t[tr][tc4 * 4 + 3] = v.w;
        }
        __syncthreads();
        int c  = tid >> 3;
        int kq = (tid & 7) * 4;
        __bf16 hv[4], lv[4];
        #pragma unroll
        for (int j = 0; j < 4; ++j) {
            float f = t[kq + j][c];
            hv[j] = (__bf16)f;
            lv[j] = (__bf16)(f - (float)hv[j]);
        }
        *reinterpret_cast<uint2*>(&Th[(size_t)(c0 + c) * D0 + k0 + kq]) = *reinterpret_cast<uint2*>(hv);
        *reinterpret_cast<uint2*>(&Tl[(size_t)(c0 + c) * D0 + k0 + kq]) = *reinterpret_cast<uint2*>(lv);
    }
}

// ---------------------------------------------------------------------------
// GEMM1 + hist fused (mutually independent, both depend only on prep):
// blocks [0,128): gemm1 128x128 tiles; blocks [128,384): edge_dst histogram.
// GEMM1: 4 waves (2x2), wave = 64x64 = 2x2 frags of 32x32x16; A (x) read as
// fp32, hi/lo split in-register.
// ---------------------------------------------------------------------------
__global__ __launch_bounds__(256) void gemm1hist_k(const float* __restrict__ X,
                                                   const __bf16* __restrict__ Wh,
                                                   const __bf16* __restrict__ Wl,
                                                   float* __restrict__ O,
                                                   const int4* __restrict__ dst4,
                                                   int* __restrict__ counts) {
    const int gid = blockIdx.x;
    const int tid = threadIdx.x;
    if (gid >= 128) {
        // histogram: 256 blocks x 256 threads x 4 edges
        int i = (gid - 128) * 256 + tid;
        int4 d = dst4[i];
        atomicAdd(&counts[d.x], 1);
        atomicAdd(&counts[d.y], 1);
        atomicAdd(&counts[d.z], 1);
        atomicAdd(&counts[d.w], 1);
        return;
    }
    const int bx = gid >> 1;          // 0..63 row-block
    const int by = gid & 1;           // 0..1  col-block
    const int lane = tid & 63;
    const int w    = tid >> 6;
    const int wm   = w >> 1;
    const int wn   = w & 1;
    const int r32  = lane & 31;
    const int kh   = lane >> 5;
    const int rowBase = bx * 128 + wm * 64;
    const int colBase = by * 128 + wn * 64;

    f32x16 acc[2][2] = {};

    for (int k0 = 0; k0 < D0; k0 += 16) {
        const int koff = k0 + kh * 8;
        bf16x8 ah[2], al[2];
        #pragma unroll
        for (int i = 0; i < 2; ++i) {
            const float* px = X + (size_t)(rowBase + i * 32 + r32) * D0 + koff;
            float4 f0 = *reinterpret_cast<const float4*>(px);
            float4 f1 = *reinterpret_cast<const float4*>(px + 4);
            float f[8] = {f0.x, f0.y, f0.z, f0.w, f1.x, f1.y, f1.z, f1.w};
            #pragma unroll
            for (int e = 0; e < 8; ++e) {
                __bf16 hj = (__bf16)f[e];
                ah[i][e] = hj;
                al[i][e] = (__bf16)(f[e] - (float)hj);
            }
        }
        bf16x8 bh[2], bl[2];
        #pragma unroll
        for (int j = 0; j < 2; ++j) {
            bh[j] = *reinterpret_cast<const bf16x8*>(Wh + (size_t)(colBase + j * 32 + r32) * D0 + koff);
            bl[j] = *reinterpret_cast<const bf16x8*>(Wl + (size_t)(colBase + j * 32 + r32) * D0 + koff);
        }
        #pragma unroll
        for (int i = 0; i < 2; ++i)
            #pragma unroll
            for (int j = 0; j < 2; ++j) {
                acc[i][j] = __builtin_amdgcn_mfma_f32_32x32x16_bf16(ah[i], bh[j], acc[i][j], 0, 0, 0);
                acc[i][j] = __builtin_amdgcn_mfma_f32_32x32x16_bf16(ah[i], bl[j], acc[i][j], 0, 0, 0);
                acc[i][j] = __builtin_amdgcn_mfma_f32_32x32x16_bf16(al[i], bh[j], acc[i][j], 0, 0, 0);
            }
    }

    #pragma unroll
    for (int i = 0; i < 2; ++i)
        #pragma unroll
        for (int j = 0; j < 2; ++j)
            #pragma unroll
            for (int reg = 0; reg < 16; ++reg) {
                int r = (reg & 3) + 8 * (reg >> 2) + 4 * kh;
                O[(size_t)(rowBase + i * 32 + r) * D1 + colBase + j * 32 + r32] = acc[i][j][reg];
            }
}

// shuffle-based scan: 256 threads x 32 counts each
__global__ __launch_bounds__(256) void scan_k(const int* __restrict__ counts,
                                              int* __restrict__ rs) {
    __shared__ int wsum[4];
    const int tid  = threadIdx.x;
    const int base = tid * 32;
    int v[32];
    int s = 0;
    #pragma unroll
    for (int j = 0; j < 8; ++j) {
        int4 q = reinterpret_cast<const int4*>(&counts[base])[j];
        v[j * 4 + 0] = q.x; v[j * 4 + 1] = q.y; v[j * 4 + 2] = q.z; v[j * 4 + 3] = q.w;
        s += q.x + q.y + q.z + q.w;
    }
    int inc = s;
    #pragma unroll
    for (int off = 1; off < 64; off <<= 1) {
        int t = __shfl_up(inc, off, 64);
        if ((tid & 63) >= off) inc += t;
    }
    if ((tid & 63) == 63) wsum[tid >> 6] = inc;
    __syncthreads();
    int wpre = 0;
    #pragma unroll
    for (int wi = 0; wi < 4; ++wi) if (wi < (tid >> 6)) wpre += wsum[wi];
    int ex = wpre + inc - s;
    #pragma unroll
    for (int j = 0; j < 32; ++j) { rs[base + j] = ex; ex += v[j]; }
    if (tid == 0) rs[NN] = NE;
}

__global__ __launch_bounds__(256) void scatter_k(const int* __restrict__ src,
                                                 const int* __restrict__ dst,
                                                 const float* __restrict__ w,
                                                 const int* __restrict__ rs,
                                                 int* __restrict__ cursor,
                                                 int* __restrict__ eps,
                                                 float* __restrict__ epw) {
    int i = blockIdx.x * 256 + threadIdx.x;
    if (i < NE) {
        int d = dst[i];
        int pos = rs[d] + atomicAdd(&cursor[d], 1);
        eps[pos] = src[i];
        epw[pos] = w[i];
    }
}

// ---------------------------------------------------------------------------
// Fused SPMM1 + relu + GEMM2 — LIGHT form (R4/R9-proven):
// one row per 256-thread block, only h1row (1KB) in LDS, W2 from L2.
// ---------------------------------------------------------------------------
__global__ __launch_bounds__(256) void spmmfuse_k(const float* __restrict__ Hin,
                                                  const int* __restrict__ rs,
                                                  const int* __restrict__ eps,
                                                  const float* __restrict__ epw,
                                                  const float* __restrict__ W2,
                                                  float* __restrict__ H1W2) {
    __shared__ float h1row[D1];
    const int row = blockIdx.x;
    const int tid = threadIdx.x;
    const int start = rs[row], end = rs[row + 1];
    float acc = 0.f;
    for (int j = start; j < end; ++j) {
        acc += epw[j] * Hin[(size_t)eps[j] * D1 + tid];
    }
    h1row[tid] = fmaxf(acc, 0.f);
    __syncthreads();
    if (tid < D2) {
        float o = 0.f;
        #pragma unroll 16
        for (int k = 0; k < D1; ++k) o += h1row[k] * W2[k * D2 + tid];
        H1W2[(size_t)row * D2 + tid] = o;
    }
}

// ---------------------------------------------------------------------------
// SPMM layer 2: emits z split into hi/lo bf16 directly.
// ---------------------------------------------------------------------------
__global__ __launch_bounds__(256) void spmm64_k(const float* __restrict__ Hin,
                                                const int* __restrict__ rs,
                                                const int* __restrict__ eps,
                                                const float* __restrict__ epw,
                                                __bf16* __restrict__ Zh,
                                                __bf16* __restrict__ Zl) {
    const int row = blockIdx.x * 4 + (threadIdx.x >> 6);
    const int c = threadIdx.x & 63;
    const int start = rs[row], end = rs[row + 1];
    float acc = 0.f;
    for (int j = start; j < end; ++j) {
        acc += epw[j] * Hin[eps[j] * D2 + c];
    }
    __bf16 h = (__bf16)acc;
    Zh[row * D2 + c] = h;
    Zl[row * D2 + c] = (__bf16)(acc - (float)h);
}

// ---------------------------------------------------------------------------
// ZZT via bf16 MFMA hi/lo split — R4-proven form: full 4096-block grid,
// no LDS, NT scalar stores (coalesced; keeps L2 clean for zh/zl operands).
//   out = zh@zh^T + zh@zl^T + zl@zh^T
// ---------------------------------------------------------------------------
__global__ __launch_bounds__(256) void zzt_k(const __bf16* __restrict__ Zh,
                                             const __bf16* __restrict__ Zl,
                                             float* __restrict__ O) {
    const int tid  = threadIdx.x;
    const int lane = tid & 63;
    const int w    = tid >> 6;
    const int wm   = w >> 1;
    const int wn   = w & 1;
    const int r32  = lane & 31;
    const int kh   = lane >> 5;
    const int rowBase = blockIdx.y * 128 + wm * 64;
    const int colBase = blockIdx.x * 128 + wn * 64;

    f32x16 acc[2][2] = {};

    #pragma unroll
    for (int kk = 0; kk < 4; ++kk) {
        const int koff = kk * 16 + kh * 8;
        bf16x8 ah0 = *reinterpret_cast<const bf16x8*>(&Zh[(rowBase +      r32) * D2 + koff]);
        bf16x8 ah1 = *reinterpret_cast<const bf16x8*>(&Zh[(rowBase + 32 + r32) * D2 + koff]);
        bf16x8 al0 = *reinterpret_cast<const bf16x8*>(&Zl[(rowBase +      r32) * D2 + koff]);
        bf16x8 al1 = *reinterpret_cast<const bf16x8*>(&Zl[(rowBase + 32 + r32) * D2 + koff]);
        bf16x8 bh0 = *reinterpret_cast<const bf16x8*>(&Zh[(colBase +      r32) * D2 + koff]);
        bf16x8 bh1 = *reinterpret_cast<const bf16x8*>(&Zh[(colBase + 32 + r32) * D2 + koff]);
        bf16x8 bl0 = *reinterpret_cast<const bf16x8*>(&Zl[(colBase +      r32) * D2 + koff]);
        bf16x8 bl1 = *reinterpret_cast<const bf16x8*>(&Zl[(colBase + 32 + r32) * D2 + koff]);

        acc[0][0] = __builtin_amdgcn_mfma_f32_32x32x16_bf16(ah0, bh0, acc[0][0], 0, 0, 0);
        acc[0][1] = __builtin_amdgcn_mfma_f32_32x32x16_bf16(ah0, bh1, acc[0][1], 0, 0, 0);
        acc[1][0] = __builtin_amdgcn_mfma_f32_32x32x16_bf16(ah1, bh0, acc[1][0], 0, 0, 0);
        acc[1][1] = __builtin_amdgcn_mfma_f32_32x32x16_bf16(ah1, bh1, acc[1][1], 0, 0, 0);

        acc[0][0] = __builtin_amdgcn_mfma_f32_32x32x16_bf16(ah0, bl0, acc[0][0], 0, 0, 0);
        acc[0][1] = __builtin_amdgcn_mfma_f32_32x32x16_bf16(ah0, bl1, acc[0][1], 0, 0, 0);
        acc[1][0] = __builtin_amdgcn_mfma_f32_32x32x16_bf16(ah1, bl0, acc[1][0], 0, 0, 0);
        acc[1][1] = __builtin_amdgcn_mfma_f32_32x32x16_bf16(ah1, bl1, acc[1][1], 0, 0, 0);

        acc[0][0] = __builtin_amdgcn_mfma_f32_32x32x16_bf16(al0, bh0, acc[0][0], 0, 0, 0);
        acc[0][1] = __builtin_amdgcn_mfma_f32_32x32x16_bf16(al0, bh1, acc[0][1], 0, 0, 0);
        acc[1][0] = __builtin_amdgcn_mfma_f32_32x32x16_bf16(al1, bh0, acc[1][0], 0, 0, 0);
        acc[1][1] = __builtin_amdgcn_mfma_f32_32x32x16_bf16(al1, bh1, acc[1][1], 0, 0, 0);
    }

    #pragma unroll
    for (int i = 0; i < 2; ++i)
        #pragma unroll
        for (int j = 0; j < 2; ++j)
            #pragma unroll
            for (int reg = 0; reg < 16; ++reg) {
                int r = (reg & 3) + 8 * (reg >> 2) + 4 * kh;
                __builtin_nontemporal_store(acc[i][j][reg],
                    &O[(size_t)(rowBase + i * 32 + r) * NN + colBase + j * 32 + r32]);
            }
}

// ---------------------------------------------------------------------------
// Launch
// ---------------------------------------------------------------------------
extern "C" void kernel_launch(void* const* d_in, const int* in_sizes, int n_in,
                              void* d_out, int out_size, void* d_ws, size_t ws_size,
                              hipStream_t stream) {
    const float* x        = (const float*)d_in[0];
    const int*   edge_src = (const int*)d_in[1];
    const int*   edge_dst = (const int*)d_in[2];
    const float* edge_w   = (const float*)d_in[3];
    const float* W1       = (const float*)d_in[4];
    const float* W2       = (const float*)d_in[5];
    float* out = (float*)d_out;

    char* ws = (char*)d_ws;
    const size_t OFF_XW1  = 0;                                  // 8 MB
    const size_t OFF_H1W2 = OFF_XW1  + (size_t)NN * D1 * 4;     // 2 MB
    const size_t OFF_ZH   = OFF_H1W2 + (size_t)NN * D2 * 4;     // 1 MB
    const size_t OFF_ZL   = OFF_ZH   + (size_t)NN * D2 * 2;     // 1 MB
    const size_t OFF_WTH  = OFF_ZL   + (size_t)NN * D2 * 2;     // 256 KB
    const size_t OFF_WTL  = OFF_WTH  + (size_t)D0 * D1 * 2;     // 256 KB
    const size_t OFF_RS   = OFF_WTL  + (size_t)D0 * D1 * 2;     // (NN+1) ints
    const size_t OFF_CNT  = OFF_RS   + 33280;                   // NN ints (zeroed)
    const size_t OFF_CUR  = OFF_CNT  + (size_t)NN * 4;          // NN ints (zeroed)
    const size_t OFF_EPS  = OFF_CUR  + (size_t)NN * 4;          // NE ints
    const size_t OFF_EPW  = OFF_EPS  + (size_t)NE * 4;          // NE floats

    float*  xw1  = (float*)(ws + OFF_XW1);
    float*  h1w2 = (float*)(ws + OFF_H1W2);
    __bf16* zh   = (__bf16*)(ws + OFF_ZH);
    __bf16* zl   = (__bf16*)(ws + OFF_ZL);
    __bf16* wth  = (__bf16*)(ws + OFF_WTH);
    __bf16* wtl  = (__bf16*)(ws + OFF_WTL);
    int*    rs   = (int*)(ws + OFF_RS);
    int*    cnt  = (int*)(ws + OFF_CNT);
    int*    cur  = (int*)(ws + OFF_CUR);
    int*    eps  = (int*)(ws + OFF_EPS);
    float*  epw  = (float*)(ws + OFF_EPW);

    // prep: zero(cnt+cur) + W1 -> W1T bf16 hi/lo
    prep_k<<<16 + 128, 256, 0, stream>>>(W1, (int4*)cnt, wth, wtl);

    // GEMM1 (128 blocks) + edge_dst histogram (256 blocks), fused
    gemm1hist_k<<<128 + 256, 256, 0, stream>>>(x, wth, wtl, xw1,
                                               (const int4*)edge_dst, cnt);

    // CSR: scan + scatter
    scan_k<<<1, 256, 0, stream>>>(cnt, rs);
    scatter_k<<<NE / 256, 256, 0, stream>>>(edge_src, edge_dst, edge_w, rs, cur, eps, epw);

    // fused SPMM1 + relu + GEMM2 (light: 1 row/block, W2 from L2)
    spmmfuse_k<<<NN, 256, 0, stream>>>(xw1, rs, eps, epw, W2, h1w2);

    // SPMM2 -> zh/zl
    spmm64_k<<<NN / 4, 256, 0, stream>>>(h1w2, rs, eps, epw, zh, zl);

    // recon = z @ z^T (full grid, NT direct stores)
    zzt_k<<<dim3(NN / 128, NN / 128), 256, 0, stream>>>(zh, zl, out);
}

// Round 11
// 211.112 us; speedup vs baseline: 2.9587x; 1.0985x over previous
//
#include <hip/hip_runtime.h>
#include <hip/hip_bf16.h>

// Problem constants
#define NN     8192      // nodes
#define D0     512       // x feature dim
#define D1     256       // hidden dim (W1 out)
#define D2     64        // z dim (W2 out)
#define NE     262144    // edges

typedef __attribute__((ext_vector_type(8)))  __bf16 bf16x8;
typedef __attribute__((ext_vector_type(16))) float  f32x16;

// ---------------------------------------------------------------------------
// prep_k: fused zero(cnt,cur) + convw1t (W1 -> W1T bf16 hi/lo)
// grid = 16 + 128 blocks
// ---------------------------------------------------------------------------
__global__ __launch_bounds__(256) void prep_k(const float* __restrict__ W,
                                              int4* __restrict__ zero_region,
                                              __bf16* __restrict__ Th,
                                              __bf16* __restrict__ Tl) {
    const int bid = blockIdx.x;
    const int tid = threadIdx.x;
    if (bid < 16) {
        zero_region[bid * 256 + tid] = make_int4(0, 0, 0, 0);
    } else {
        __shared__ float t[32][33];
        const int cid = bid - 16;
        const int c0 = (cid & 7) * 32;      // D1/32 = 8
        const int k0 = (cid >> 3) * 32;     // D0/32 = 16
        {
            int tr  = tid >> 3;
            int tc4 = tid & 7;
            float4 v = *reinterpret_cast<const float4*>(&W[(k0 + tr) * D1 + c0 + tc4 * 4]);
            t[tr][tc4 * 4 + 0] = v.x;
            t[tr][tc4 * 4 + 1] = v.y;
            t[tr][tc4 * 4 + 2] = v.z;
            t[tr][tc4 * 4 + 3] = v.w;
        }
        __syncthreads();
        int c  = tid >> 3;
        int kq = (tid & 7) * 4;
        __bf16 hv[4], lv[4];
        #pragma unroll
        for (int j = 0; j < 4; ++j) {
            float f = t[kq + j][c];
            hv[j] = (__bf16)f;
            lv[j] = (__bf16)(f - (float)hv[j]);
        }
        *reinterpret_cast<uint2*>(&Th[(size_t)(c0 + c) * D0 + k0 + kq]) = *reinterpret_cast<uint2*>(hv);
        *reinterpret_cast<uint2*>(&Tl[(size_t)(c0 + c) * D0 + k0 + kq]) = *reinterpret_cast<uint2*>(lv);
    }
}

// ---------------------------------------------------------------------------
// GEMM1 + hist fused: blocks [0,128) gemm1 128x128 tiles; [128,384) histogram.
// ---------------------------------------------------------------------------
__global__ __launch_bounds__(256) void gemm1hist_k(const float* __restrict__ X,
                                                   const __bf16* __restrict__ Wh,
                                                   const __bf16* __restrict__ Wl,
                                                   float* __restrict__ O,
                                                   const int4* __restrict__ dst4,
                                                   int* __restrict__ counts) {
    const int gid = blockIdx.x;
    const int tid = threadIdx.x;
    if (gid >= 128) {
        int i = (gid - 128) * 256 + tid;
        int4 d = dst4[i];
        atomicAdd(&counts[d.x], 1);
        atomicAdd(&counts[d.y], 1);
        atomicAdd(&counts[d.z], 1);
        atomicAdd(&counts[d.w], 1);
        return;
    }
    const int bx = gid >> 1;
    const int by = gid & 1;
    const int lane = tid & 63;
    const int w    = tid >> 6;
    const int wm   = w >> 1;
    const int wn   = w & 1;
    const int r32  = lane & 31;
    const int kh   = lane >> 5;
    const int rowBase = bx * 128 + wm * 64;
    const int colBase = by * 128 + wn * 64;

    f32x16 acc[2][2] = {};

    for (int k0 = 0; k0 < D0; k0 += 16) {
        const int koff = k0 + kh * 8;
        bf16x8 ah[2], al[2];
        #pragma unroll
        for (int i = 0; i < 2; ++i) {
            const float* px = X + (size_t)(rowBase + i * 32 + r32) * D0 + koff;
            float4 f0 = *reinterpret_cast<const float4*>(px);
            float4 f1 = *reinterpret_cast<const float4*>(px + 4);
            float f[8] = {f0.x, f0.y, f0.z, f0.w, f1.x, f1.y, f1.z, f1.w};
            #pragma unroll
            for (int e = 0; e < 8; ++e) {
                __bf16 hj = (__bf16)f[e];
                ah[i][e] = hj;
                al[i][e] = (__bf16)(f[e] - (float)hj);
            }
        }
        bf16x8 bh[2], bl[2];
        #pragma unroll
        for (int j = 0; j < 2; ++j) {
            bh[j] = *reinterpret_cast<const bf16x8*>(Wh + (size_t)(colBase + j * 32 + r32) * D0 + koff);
            bl[j] = *reinterpret_cast<const bf16x8*>(Wl + (size_t)(colBase + j * 32 + r32) * D0 + koff);
        }
        #pragma unroll
        for (int i = 0; i < 2; ++i)
            #pragma unroll
            for (int j = 0; j < 2; ++j) {
                acc[i][j] = __builtin_amdgcn_mfma_f32_32x32x16_bf16(ah[i], bh[j], acc[i][j], 0, 0, 0);
                acc[i][j] = __builtin_amdgcn_mfma_f32_32x32x16_bf16(ah[i], bl[j], acc[i][j], 0, 0, 0);
                acc[i][j] = __builtin_amdgcn_mfma_f32_32x32x16_bf16(al[i], bh[j], acc[i][j], 0, 0, 0);
            }
    }

    #pragma unroll
    for (int i = 0; i < 2; ++i)
        #pragma unroll
        for (int j = 0; j < 2; ++j)
            #pragma unroll
            for (int reg = 0; reg < 16; ++reg) {
                int r = (reg & 3) + 8 * (reg >> 2) + 4 * kh;
                O[(size_t)(rowBase + i * 32 + r) * D1 + colBase + j * 32 + r32] = acc[i][j][reg];
            }
}

// shuffle-based scan: 256 threads x 32 counts each
__global__ __launch_bounds__(256) void scan_k(const int* __restrict__ counts,
                                              int* __restrict__ rs) {
    __shared__ int wsum[4];
    const int tid  = threadIdx.x;
    const int base = tid * 32;
    int v[32];
    int s = 0;
    #pragma unroll
    for (int j = 0; j < 8; ++j) {
        int4 q = reinterpret_cast<const int4*>(&counts[base])[j];
        v[j * 4 + 0] = q.x; v[j * 4 + 1] = q.y; v[j * 4 + 2] = q.z; v[j * 4 + 3] = q.w;
        s += q.x + q.y + q.z + q.w;
    }
    int inc = s;
    #pragma unroll
    for (int off = 1; off < 64; off <<= 1) {
        int t = __shfl_up(inc, off, 64);
        if ((tid & 63) >= off) inc += t;
    }
    if ((tid & 63) == 63) wsum[tid >> 6] = inc;
    __syncthreads();
    int wpre = 0;
    #pragma unroll
    for (int wi = 0; wi < 4; ++wi) if (wi < (tid >> 6)) wpre += wsum[wi];
    int ex = wpre + inc - s;
    #pragma unroll
    for (int j = 0; j < 32; ++j) { rs[base + j] = ex; ex += v[j]; }
    if (tid == 0) rs[NN] = NE;
}

// scatter: 4 edges per thread (int4/float4 loads)
__global__ __launch_bounds__(256) void scatter_k(const int4* __restrict__ src4,
                                                 const int4* __restrict__ dst4,
                                                 const float4* __restrict__ w4,
                                                 const int* __restrict__ rs,
                                                 int* __restrict__ cursor,
                                                 int* __restrict__ eps,
                                                 float* __restrict__ epw) {
    int i = blockIdx.x * 256 + threadIdx.x;   // grid = NE/4/256 = 256
    int4   s = src4[i];
    int4   d = dst4[i];
    float4 w = w4[i];
    int p;
    p = rs[d.x] + atomicAdd(&cursor[d.x], 1); eps[p] = s.x; epw[p] = w.x;
    p = rs[d.y] + atomicAdd(&cursor[d.y], 1); eps[p] = s.y; epw[p] = w.y;
    p = rs[d.z] + atomicAdd(&cursor[d.z], 1); eps[p] = s.z; epw[p] = w.z;
    p = rs[d.w] + atomicAdd(&cursor[d.w], 1); eps[p] = s.w; epw[p] = w.w;
}

// ---------------------------------------------------------------------------
// Fused SPMM1 + relu + GEMM2 — float4 gather, 4 rows/block.
// Each 64-thread group owns one row (wave-uniform edge loop); thread loads
// float4 (1KB/row burst, 4 independent gather streams per block).
// GEMM2 tail: all 256 threads (row = tid>>6, c = tid&63).
// ---------------------------------------------------------------------------
__global__ __launch_bounds__(256) void spmmfuse_k(const float* __restrict__ Hin,
                                                  const int* __restrict__ rs,
                                                  const int* __restrict__ eps,
                                                  const float* __restrict__ epw,
                                                  const float* __restrict__ W2,
                                                  float* __restrict__ H1W2) {
    __shared__ float h1row[4][D1];
    const int tid = threadIdx.x;
    const int g   = tid >> 6;          // row group 0..3
    const int lc  = (tid & 63) * 4;    // col (float4)
    const int row = blockIdx.x * 4 + g;
    const int start = rs[row], end = rs[row + 1];
    float4 acc = make_float4(0.f, 0.f, 0.f, 0.f);
    for (int j = start; j < end; ++j) {
        const float w = epw[j];
        float4 v = *reinterpret_cast<const float4*>(&Hin[(size_t)eps[j] * D1 + lc]);
        acc.x += w * v.x; acc.y += w * v.y; acc.z += w * v.z; acc.w += w * v.w;
    }
    h1row[g][lc + 0] = fmaxf(acc.x, 0.f);
    h1row[g][lc + 1] = fmaxf(acc.y, 0.f);
    h1row[g][lc + 2] = fmaxf(acc.z, 0.f);
    h1row[g][lc + 3] = fmaxf(acc.w, 0.f);
    __syncthreads();
    // gemm2: row = tid>>6, c = tid&63 (all 256 threads busy)
    const int c = tid & 63;
    float o = 0.f;
    #pragma unroll 16
    for (int k = 0; k < D1; ++k) o += h1row[g][k] * W2[k * D2 + c];
    H1W2[(size_t)row * D2 + c] = o;
}

// ---------------------------------------------------------------------------
// SPMM layer 2 — float4 gather, 16 rows/block (16 threads/row).
// Emits z split into hi/lo bf16 (4 cols -> one 8B store each).
// ---------------------------------------------------------------------------
__global__ __launch_bounds__(256) void spmm64_k(const float* __restrict__ Hin,
                                                const int* __restrict__ rs,
                                                const int* __restrict__ eps,
                                                const float* __restrict__ epw,
                                                __bf16* __restrict__ Zh,
                                                __bf16* __restrict__ Zl) {
    const int tid = threadIdx.x;
    const int g   = tid >> 4;          // row group 0..15
    const int lc  = (tid & 15) * 4;    // col (float4)
    const int row = blockIdx.x * 16 + g;
    const int start = rs[row], end = rs[row + 1];
    float4 acc = make_float4(0.f, 0.f, 0.f, 0.f);
    for (int j = start; j < end; ++j) {
        const float w = epw[j];
        float4 v = *reinterpret_cast<const float4*>(&Hin[(size_t)eps[j] * D2 + lc]);
        acc.x += w * v.x; acc.y += w * v.y; acc.z += w * v.z; acc.w += w * v.w;
    }
    float a[4] = {acc.x, acc.y, acc.z, acc.w};
    __bf16 h4[4], l4[4];
    #pragma unroll
    for (int e = 0; e < 4; ++e) {
        __bf16 h = (__bf16)a[e];
        h4[e] = h;
        l4[e] = (__bf16)(a[e] - (float)h);
    }
    *reinterpret_cast<uint2*>(&Zh[(size_t)row * D2 + lc]) = *reinterpret_cast<uint2*>(h4);
    *reinterpret_cast<uint2*>(&Zl[(size_t)row * D2 + lc]) = *reinterpret_cast<uint2*>(l4);
}

// ---------------------------------------------------------------------------
// ZZT via bf16 MFMA hi/lo split — R4/R10-proven form: full 4096-block grid,
// no LDS, NT scalar stores.
//   out = zh@zh^T + zh@zl^T + zl@zh^T
// ---------------------------------------------------------------------------
__global__ __launch_bounds__(256) void zzt_k(const __bf16* __restrict__ Zh,
                                             const __bf16* __restrict__ Zl,
                                             float* __restrict__ O) {
    const int tid  = threadIdx.x;
    const int lane = tid & 63;
    const int w    = tid >> 6;
    const int wm   = w >> 1;
    const int wn   = w & 1;
    const int r32  = lane & 31;
    const int kh   = lane >> 5;
    const int rowBase = blockIdx.y * 128 + wm * 64;
    const int colBase = blockIdx.x * 128 + wn * 64;

    f32x16 acc[2][2] = {};

    #pragma unroll
    for (int kk = 0; kk < 4; ++kk) {
        const int koff = kk * 16 + kh * 8;
        bf16x8 ah0 = *reinterpret_cast<const bf16x8*>(&Zh[(rowBase +      r32) * D2 + koff]);
        bf16x8 ah1 = *reinterpret_cast<const bf16x8*>(&Zh[(rowBase + 32 + r32) * D2 + koff]);
        bf16x8 al0 = *reinterpret_cast<const bf16x8*>(&Zl[(rowBase +      r32) * D2 + koff]);
        bf16x8 al1 = *reinterpret_cast<const bf16x8*>(&Zl[(rowBase + 32 + r32) * D2 + koff]);
        bf16x8 bh0 = *reinterpret_cast<const bf16x8*>(&Zh[(colBase +      r32) * D2 + koff]);
        bf16x8 bh1 = *reinterpret_cast<const bf16x8*>(&Zh[(colBase + 32 + r32) * D2 + koff]);
        bf16x8 bl0 = *reinterpret_cast<const bf16x8*>(&Zl[(colBase +      r32) * D2 + koff]);
        bf16x8 bl1 = *reinterpret_cast<const bf16x8*>(&Zl[(colBase + 32 + r32) * D2 + koff]);

        acc[0][0] = __builtin_amdgcn_mfma_f32_32x32x16_bf16(ah0, bh0, acc[0][0], 0, 0, 0);
        acc[0][1] = __builtin_amdgcn_mfma_f32_32x32x16_bf16(ah0, bh1, acc[0][1], 0, 0, 0);
        acc[1][0] = __builtin_amdgcn_mfma_f32_32x32x16_bf16(ah1, bh0, acc[1][0], 0, 0, 0);
        acc[1][1] = __builtin_amdgcn_mfma_f32_32x32x16_bf16(ah1, bh1, acc[1][1], 0, 0, 0);

        acc[0][0] = __builtin_amdgcn_mfma_f32_32x32x16_bf16(ah0, bl0, acc[0][0], 0, 0, 0);
        acc[0][1] = __builtin_amdgcn_mfma_f32_32x32x16_bf16(ah0, bl1, acc[0][1], 0, 0, 0);
        acc[1][0] = __builtin_amdgcn_mfma_f32_32x32x16_bf16(ah1, bl0, acc[1][0], 0, 0, 0);
        acc[1][1] = __builtin_amdgcn_mfma_f32_32x32x16_bf16(ah1, bl1, acc[1][1], 0, 0, 0);

        acc[0][0] = __builtin_amdgcn_mfma_f32_32x32x16_bf16(al0, bh0, acc[0][0], 0, 0, 0);
        acc[0][1] = __builtin_amdgcn_mfma_f32_32x32x16_bf16(al0, bh1, acc[0][1], 0, 0, 0);
        acc[1][0] = __builtin_amdgcn_mfma_f32_32x32x16_bf16(al1, bh0, acc[1][0], 0, 0, 0);
        acc[1][1] = __builtin_amdgcn_mfma_f32_32x32x16_bf16(al1, bh1, acc[1][1], 0, 0, 0);
    }

    #pragma unroll
    for (int i = 0; i < 2; ++i)
        #pragma unroll
        for (int j = 0; j < 2; ++j)
            #pragma unroll
            for (int reg = 0; reg < 16; ++reg) {
                int r = (reg & 3) + 8 * (reg >> 2) + 4 * kh;
                __builtin_nontemporal_store(acc[i][j][reg],
                    &O[(size_t)(rowBase + i * 32 + r) * NN + colBase + j * 32 + r32]);
            }
}

// ---------------------------------------------------------------------------
// Launch
// ---------------------------------------------------------------------------
extern "C" void kernel_launch(void* const* d_in, const int* in_sizes, int n_in,
                              void* d_out, int out_size, void* d_ws, size_t ws_size,
                              hipStream_t stream) {
    const float* x        = (const float*)d_in[0];
    const int*   edge_src = (const int*)d_in[1];
    const int*   edge_dst = (const int*)d_in[2];
    const float* edge_w   = (const float*)d_in[3];
    const float* W1       = (const float*)d_in[4];
    const float* W2       = (const float*)d_in[5];
    float* out = (float*)d_out;

    char* ws = (char*)d_ws;
    const size_t OFF_XW1  = 0;                                  // 8 MB
    const size_t OFF_H1W2 = OFF_XW1  + (size_t)NN * D1 * 4;     // 2 MB
    const size_t OFF_ZH   = OFF_H1W2 + (size_t)NN * D2 * 4;     // 1 MB
    const size_t OFF_ZL   = OFF_ZH   + (size_t)NN * D2 * 2;     // 1 MB
    const size_t OFF_WTH  = OFF_ZL   + (size_t)NN * D2 * 2;     // 256 KB
    const size_t OFF_WTL  = OFF_WTH  + (size_t)D0 * D1 * 2;     // 256 KB
    const size_t OFF_RS   = OFF_WTL  + (size_t)D0 * D1 * 2;     // (NN+1) ints
    const size_t OFF_CNT  = OFF_RS   + 33280;                   // NN ints (zeroed)
    const size_t OFF_CUR  = OFF_CNT  + (size_t)NN * 4;          // NN ints (zeroed)
    const size_t OFF_EPS  = OFF_CUR  + (size_t)NN * 4;          // NE ints
    const size_t OFF_EPW  = OFF_EPS  + (size_t)NE * 4;          // NE floats

    float*  xw1  = (float*)(ws + OFF_XW1);
    float*  h1w2 = (float*)(ws + OFF_H1W2);
    __bf16* zh   = (__bf16*)(ws + OFF_ZH);
    __bf16* zl   = (__bf16*)(ws + OFF_ZL);
    __bf16* wth  = (__bf16*)(ws + OFF_WTH);
    __bf16* wtl  = (__bf16*)(ws + OFF_WTL);
    int*    rs   = (int*)(ws + OFF_RS);
    int*    cnt  = (int*)(ws + OFF_CNT);
    int*    cur  = (int*)(ws + OFF_CUR);
    int*    eps  = (int*)(ws + OFF_EPS);
    float*  epw  = (float*)(ws + OFF_EPW);

    // prep: zero(cnt+cur) + W1 -> W1T bf16 hi/lo
    prep_k<<<16 + 128, 256, 0, stream>>>(W1, (int4*)cnt, wth, wtl);

    // GEMM1 (128 blocks) + edge_dst histogram (256 blocks), fused
    gemm1hist_k<<<128 + 256, 256, 0, stream>>>(x, wth, wtl, xw1,
                                               (const int4*)edge_dst, cnt);

    // CSR: scan + scatter (4 edges/thread)
    scan_k<<<1, 256, 0, stream>>>(cnt, rs);
    scatter_k<<<NE / 4 / 256, 256, 0, stream>>>((const int4*)edge_src,
                                                (const int4*)edge_dst,
                                                (const float4*)edge_w,
                                                rs, cur, eps, epw);

    // fused SPMM1 + relu + GEMM2 (float4 gather, 4 rows/block)
    spmmfuse_k<<<NN / 4, 256, 0, stream>>>(xw1, rs, eps, epw, W2, h1w2);

    // SPMM2 -> zh/zl (float4 gather, 16 rows/block)
    spmm64_k<<<NN / 16, 256, 0, stream>>>(h1w2, rs, eps, epw, zh, zl);

    // recon = z @ z^T (full grid, NT direct stores)
    zzt_k<<<dim3(NN / 128, NN / 128), 256, 0, stream>>>(zh, zl, out);
}